// Round 2
// baseline (928.815 us; speedup 1.0000x reference)
//
#include <hip/hip_runtime.h>
#include <hip/hip_bf16.h>

typedef __bf16 bf16x8 __attribute__((ext_vector_type(8)));
typedef __bf16 bf16x4 __attribute__((ext_vector_type(4)));
typedef float  f32x4  __attribute__((ext_vector_type(4)));

#define MFMA16(a, b, c) __builtin_amdgcn_mfma_f32_16x16x32_bf16((a), (b), (c), 0, 0, 0)

// ---------------------------------------------------------------------------
// zero the stats scratch (32 floats: stats1[16] + stats2[16])
__global__ void zero_stats_kernel(float* s) { s[threadIdx.x] = 0.0f; }

// ---------------------------------------------------------------------------
// Fused: GN1 stats (per-group sum/sumsq over f32 x) + cast x -> bf16 copy xb.
// x is [N,32] row-major; a float4 covers 4 consecutive channels, all in one
// group (4 ch/group). Grid stride is a multiple of 8 float4s, so each thread
// touches exactly one group g = gt&7.
__global__ __launch_bounds__(256) void caststats_kernel(
    const float4* __restrict__ x, bf16x4* __restrict__ xb,
    float* __restrict__ stats, int nvec)
{
    int nth = gridDim.x * blockDim.x;
    int gt = blockIdx.x * blockDim.x + threadIdx.x;
    float s = 0.f, ss = 0.f;
    for (int f = gt; f < nvec; f += nth) {
        float4 v = x[f];
        s  += v.x + v.y + v.z + v.w;
        ss += v.x * v.x + v.y * v.y + v.z * v.z + v.w * v.w;
        bf16x4 b;
        b[0] = (__bf16)v.x; b[1] = (__bf16)v.y;
        b[2] = (__bf16)v.z; b[3] = (__bf16)v.w;
        xb[f] = b;
    }
    __shared__ float ls[16];
    if (threadIdx.x < 16) ls[threadIdx.x] = 0.f;
    __syncthreads();
    int g = gt & 7;
    atomicAdd(&ls[2 * g], s);
    atomicAdd(&ls[2 * g + 1], ss);
    __syncthreads();
    if (threadIdx.x < 16) atomicAdd(&stats[threadIdx.x], ls[threadIdx.x]);
}

// ---------------------------------------------------------------------------
// Fold GN1 affine into W1 (bf16 B-fragment pack), pack Wskip, conv1 bias,
// forward feat_depth.  B-frag (mfma_f32_16x16x32_bf16): lane holds
// B[k=(lane>>4)*8+j][n=lane&15].  bp1 index: [k][ct][lane][j] (27*4*64*8)
__global__ __launch_bounds__(256) void fold1_kernel(
    const float* __restrict__ W1, const float* __restrict__ gamma1,
    const float* __restrict__ beta1, const float* __restrict__ Wskip,
    const float* __restrict__ stats1,
    __bf16* __restrict__ bp1, __bf16* __restrict__ bps,
    float* __restrict__ bias1,
    const int* __restrict__ feat, int* __restrict__ feat_out, float inv_n)
{
    int b = blockIdx.x, t = threadIdx.x;
    if (b < 216) {                      // pack a1*W1 : 216*256 = 55296 elements
        int e = b * 256 + t;
        int j = e & 7, lane = (e >> 3) & 63, ct = (e >> 9) & 3, k = e >> 11;
        int ci = ((lane >> 4) << 3) + j;
        int co = (ct << 4) + (lane & 15);
        int g = ci >> 2;
        float mean = stats1[2 * g] * inv_n;
        float var  = stats1[2 * g + 1] * inv_n - mean * mean;
        float r = rsqrtf(var + 1e-5f);
        float a = gamma1[ci] * r;
        bp1[e] = (__bf16)(a * W1[k * 2048 + ci * 64 + co]);
    } else if (b == 216) {              // bias1[co] = sum_ci b1[ci] * sum_k W1[k,ci,co]
        if (t < 64) {
            float sum = 0.0f;
            for (int ci = 0; ci < 32; ++ci) {
                int g = ci >> 2;
                float mean = stats1[2 * g] * inv_n;
                float var  = stats1[2 * g + 1] * inv_n - mean * mean;
                float r = rsqrtf(var + 1e-5f);
                float a = gamma1[ci] * r;
                float bb = beta1[ci] - mean * a;
                float ws = 0.0f;
                for (int k = 0; k < 27; ++k) ws += W1[k * 2048 + ci * 64 + t];
                sum += bb * ws;
            }
            bias1[t] = sum;
        } else if (t == 64) {
            feat_out[0] = feat[0];      // feat_depth == 0
        }
    } else {                            // pack Wskip: 8 blocks, 2048 elements
        int e = (b - 217) * 256 + t;
        int j = e & 7, lane = (e >> 3) & 63, ct = e >> 9;
        int ci = ((lane >> 4) << 3) + j;
        int co = (ct << 4) + (lane & 15);
        bps[e] = (__bf16)Wskip[ci * 64 + co];
    }
}

// ---------------------------------------------------------------------------
// Fold GN2 into W2.  bp2 index: [k][hf][ct][lane][j]  (27*2*4*64*8)
__global__ __launch_bounds__(256) void fold2_kernel(
    const float* __restrict__ W2, const float* __restrict__ gamma2,
    const float* __restrict__ beta2, const float* __restrict__ stats2,
    __bf16* __restrict__ bp2, float* __restrict__ bias2, float inv_n)
{
    int b = blockIdx.x, t = threadIdx.x;
    if (b < 432) {                      // 432*256 = 110592 elements
        int e = b * 256 + t;
        int j = e & 7, lane = (e >> 3) & 63, ct = (e >> 9) & 3, hf = (e >> 11) & 1, k = e >> 12;
        int ci = (hf << 5) + ((lane >> 4) << 3) + j;
        int co = (ct << 4) + (lane & 15);
        int g = ci >> 3;
        float mean = stats2[2 * g] * inv_n;
        float var  = stats2[2 * g + 1] * inv_n - mean * mean;
        float r = rsqrtf(var + 1e-5f);
        float a = gamma2[ci] * r;
        bp2[e] = (__bf16)(a * W2[k * 4096 + ci * 64 + co]);
    } else if (t < 64) {
        float sum = 0.0f;
        for (int ci = 0; ci < 64; ++ci) {
            int g = ci >> 3;
            float mean = stats2[2 * g] * inv_n;
            float var  = stats2[2 * g + 1] * inv_n - mean * mean;
            float r = rsqrtf(var + 1e-5f);
            float a = gamma2[ci] * r;
            float bb = beta2[ci] - mean * a;
            float ws = 0.0f;
            for (int k = 0; k < 27; ++k) ws += W2[k * 4096 + ci * 64 + t];
            sum += bb * ws;
        }
        bias2[t] = sum;
    }
}

// ---------------------------------------------------------------------------
// conv1: h[n,:64] = silu( sum_k xb[idx[n,k],:32] @ W1'[k] + bias1 )  (h bf16)
// Also accumulates GN2 stats (per-group sum/sumsq of the f32 h values).
// One wave per 16-voxel tile; A-fragment is a direct gathered 16B load.
__global__ __launch_bounds__(256) void conv1_kernel(
    const __bf16* __restrict__ xb, const int* __restrict__ nbr,
    const __bf16* __restrict__ bp1, const float* __restrict__ bias1,
    __bf16* __restrict__ h, float* __restrict__ stats2, int N)
{
    __shared__ int sidx[4][27 * 16];
    __shared__ float ls[16];
    const int wav = threadIdx.x >> 6, lane = threadIdx.x & 63;
    const int v0 = (blockIdx.x * 4 + wav) * 16;
    const bool act = v0 < N;
    if (threadIdx.x < 16) ls[threadIdx.x] = 0.f;
    const int lm = lane & 15, q = lane >> 4;
    f32x4 acc0 = {0.f,0.f,0.f,0.f}, acc1 = acc0, acc2 = acc0, acc3 = acc0;
    if (act) {
        const int* gi = nbr + (size_t)v0 * 27;
        for (int i = lane; i < 432; i += 64) sidx[wav][i] = gi[i];
        const bf16x8* __restrict__ bpv = (const bf16x8*)bp1;
        for (int k = 0; k < 27; ++k) {
            int nb = sidx[wav][lm * 27 + k];
            bf16x8 a = *(const bf16x8*)(xb + (size_t)nb * 32 + q * 8);
            int bb = k * 256 + lane;
            acc0 = MFMA16(a, bpv[bb],       acc0);
            acc1 = MFMA16(a, bpv[bb + 64],  acc1);
            acc2 = MFMA16(a, bpv[bb + 128], acc2);
            acc3 = MFMA16(a, bpv[bb + 192], acc3);
        }
    }
    __syncthreads();        // ls zero visible to all
    if (act) {
        // C/D layout: col = lane&15 (cout), row = q*4 + r (voxel)
#define EPI1(ACC, CT) { \
        float bsv = bias1[(CT) * 16 + lm]; \
        float ps = 0.f, pss = 0.f; \
        _Pragma("unroll") \
        for (int r = 0; r < 4; ++r) { \
            float val = ACC[r] + bsv; \
            val = val / (1.0f + __expf(-val)); \
            h[(size_t)(v0 + q * 4 + r) * 64 + (CT) * 16 + lm] = (__bf16)val; \
            ps += val; pss += val * val; } \
        int g2 = (CT) * 2 + (lm >> 3); \
        atomicAdd(&ls[2 * g2], ps); atomicAdd(&ls[2 * g2 + 1], pss); }
        EPI1(acc0, 0) EPI1(acc1, 1) EPI1(acc2, 2) EPI1(acc3, 3)
#undef EPI1
    }
    __syncthreads();
    if (threadIdx.x < 16) atomicAdd(&stats2[threadIdx.x], ls[threadIdx.x]);
}

// ---------------------------------------------------------------------------
// conv2 + skip: out = silu( sum_k h[idx[n,k]] @ W2'[k] + bias2 ) + xb[n]@Wskip + bskip
__global__ __launch_bounds__(256) void conv2_kernel(
    const __bf16* __restrict__ h, const __bf16* __restrict__ xb,
    const int* __restrict__ nbr,
    const __bf16* __restrict__ bp2, const __bf16* __restrict__ bps,
    const float* __restrict__ bias2, const float* __restrict__ bskip,
    float* __restrict__ out, int N)
{
    __shared__ int sidx[4][27 * 16];
    const int wav = threadIdx.x >> 6, lane = threadIdx.x & 63;
    const int v0 = (blockIdx.x * 4 + wav) * 16;
    if (v0 >= N) return;
    const int* gi = nbr + (size_t)v0 * 27;
    for (int i = lane; i < 432; i += 64) sidx[wav][i] = gi[i];
    const int lm = lane & 15, q = lane >> 4;
    f32x4 c0 = {0.f,0.f,0.f,0.f}, c1 = c0, c2 = c0, c3 = c0;
    f32x4 s0 = c0, s1 = c0, s2 = c0, s3 = c0;
    const bf16x8* __restrict__ bpv = (const bf16x8*)bp2;
    const bf16x8* __restrict__ bsp = (const bf16x8*)bps;
    {   // skip 1x1 conv: A rows are this tile's own xb rows
        bf16x8 ax = *(const bf16x8*)(xb + (size_t)(v0 + lm) * 32 + q * 8);
        s0 = MFMA16(ax, bsp[lane],       s0);
        s1 = MFMA16(ax, bsp[64 + lane],  s1);
        s2 = MFMA16(ax, bsp[128 + lane], s2);
        s3 = MFMA16(ax, bsp[192 + lane], s3);
    }
    for (int k = 0; k < 27; ++k) {
        int nb = sidx[wav][lm * 27 + k];
        const __bf16* hr = h + (size_t)nb * 64;
        bf16x8 a0 = *(const bf16x8*)(hr + q * 8);        // ci 0..31
        bf16x8 a1 = *(const bf16x8*)(hr + 32 + q * 8);   // ci 32..63
        int bb = k * 512 + lane;
        c0 = MFMA16(a0, bpv[bb],       c0);
        c1 = MFMA16(a0, bpv[bb + 64],  c1);
        c2 = MFMA16(a0, bpv[bb + 128], c2);
        c3 = MFMA16(a0, bpv[bb + 192], c3);
        c0 = MFMA16(a1, bpv[bb + 256], c0);
        c1 = MFMA16(a1, bpv[bb + 320], c1);
        c2 = MFMA16(a1, bpv[bb + 384], c2);
        c3 = MFMA16(a1, bpv[bb + 448], c3);
    }
#define EPI2(CC, SS, CT) { \
        int co = (CT) * 16 + lm; \
        float b2v = bias2[co]; \
        float bsk = bskip[co]; \
        _Pragma("unroll") \
        for (int r = 0; r < 4; ++r) { \
            float val = CC[r] + b2v; \
            val = val / (1.0f + __expf(-val)); \
            val += SS[r] + bsk; \
            out[(size_t)(v0 + q * 4 + r) * 64 + co] = val; } }
    EPI2(c0, s0, 0) EPI2(c1, s1, 1) EPI2(c2, s2, 2) EPI2(c3, s3, 3)
#undef EPI2
}

// ---------------------------------------------------------------------------
extern "C" void kernel_launch(void* const* d_in, const int* in_sizes, int n_in,
                              void* d_out, int out_size, void* d_ws, size_t ws_size,
                              hipStream_t stream)
{
    (void)n_in; (void)out_size; (void)ws_size;
    const float* x      = (const float*)d_in[0];
    const int*   nbr    = (const int*)d_in[1];
    const float* gamma1 = (const float*)d_in[2];
    const float* beta1  = (const float*)d_in[3];
    const float* W1     = (const float*)d_in[4];
    const float* gamma2 = (const float*)d_in[5];
    const float* beta2  = (const float*)d_in[6];
    const float* W2     = (const float*)d_in[7];
    const float* Wskip  = (const float*)d_in[8];
    const float* bskip  = (const float*)d_in[9];
    const int*   feat   = (const int*)d_in[10];
    const int N = in_sizes[0] / 32;

    char* ws = (char*)d_ws;
    float* stats1 = (float*)ws;                 // 16 floats
    float* stats2 = stats1 + 16;                // 16 floats
    float* bias1  = stats1 + 32;                // 64 floats
    float* bias2  = stats1 + 96;                // 64 floats
    __bf16* bp1 = (__bf16*)(ws + (1 << 10));    // 55296 elems = 110592 B
    __bf16* bps = (__bf16*)(ws + (1 << 17));    // 2048 elems
    __bf16* bp2 = (__bf16*)(ws + 144 * 1024);   // 110592 elems = 221184 B
    __bf16* xb  = (__bf16*)(ws + (1 << 20));    // N*32 bf16 = 32 MB
    __bf16* h   = (__bf16*)(ws + (size_t)34 * (1 << 20)); // N*64 bf16 = 64 MB
    float* outb = (float*)d_out;

    const int convBlocks = (N / 16 + 3) / 4;

    hipLaunchKernelGGL(zero_stats_kernel, dim3(1), dim3(32), 0, stream, stats1);
    hipLaunchKernelGGL(caststats_kernel, dim3(2048), dim3(256), 0, stream,
                       (const float4*)x, (bf16x4*)xb, stats1, N * 8);
    hipLaunchKernelGGL(fold1_kernel, dim3(225), dim3(256), 0, stream,
                       W1, gamma1, beta1, Wskip, stats1, bp1, bps, bias1,
                       feat, (int*)(outb + (size_t)N * 64),
                       1.0f / (4.0f * (float)N));
    hipLaunchKernelGGL(conv1_kernel, dim3(convBlocks), dim3(256), 0, stream,
                       xb, nbr, bp1, bias1, h, stats2, N);
    hipLaunchKernelGGL(fold2_kernel, dim3(433), dim3(256), 0, stream,
                       W2, gamma2, beta2, stats2, bp2, bias2,
                       1.0f / (8.0f * (float)N));
    hipLaunchKernelGGL(conv2_kernel, dim3(convBlocks), dim3(256), 0, stream,
                       h, xb, nbr, bp2, bps, bias2, bskip, outb, N);
}

// Round 3
// 864.268 us; speedup vs baseline: 1.0747x; 1.0747x over previous
//
#include <hip/hip_runtime.h>
#include <hip/hip_bf16.h>

typedef __bf16 bf16x8 __attribute__((ext_vector_type(8)));
typedef __bf16 bf16x4 __attribute__((ext_vector_type(4)));
typedef float  f32x4  __attribute__((ext_vector_type(4)));

#define MFMA16(a, b, c) __builtin_amdgcn_mfma_f32_16x16x32_bf16((a), (b), (c), 0, 0, 0)

// ---------------------------------------------------------------------------
__global__ void zero_stats_kernel(float* s) { s[threadIdx.x] = 0.0f; }

// ---------------------------------------------------------------------------
// Fused: GN1 stats (per-group sum/sumsq over f32 x) + cast x -> bf16 copy xb.
__global__ __launch_bounds__(256) void caststats_kernel(
    const float4* __restrict__ x, bf16x4* __restrict__ xb,
    float* __restrict__ stats, int nvec)
{
    int nth = gridDim.x * blockDim.x;
    int gt = blockIdx.x * blockDim.x + threadIdx.x;
    float s = 0.f, ss = 0.f;
    for (int f = gt; f < nvec; f += nth) {
        float4 v = x[f];
        s  += v.x + v.y + v.z + v.w;
        ss += v.x * v.x + v.y * v.y + v.z * v.z + v.w * v.w;
        bf16x4 b;
        b[0] = (__bf16)v.x; b[1] = (__bf16)v.y;
        b[2] = (__bf16)v.z; b[3] = (__bf16)v.w;
        xb[f] = b;
    }
    __shared__ float ls[16];
    if (threadIdx.x < 16) ls[threadIdx.x] = 0.f;
    __syncthreads();
    int g = gt & 7;
    atomicAdd(&ls[2 * g], s);
    atomicAdd(&ls[2 * g + 1], ss);
    __syncthreads();
    if (threadIdx.x < 16) atomicAdd(&stats[threadIdx.x], ls[threadIdx.x]);
}

// ---------------------------------------------------------------------------
// Fold GN1 affine into W1 (bf16 B-frag pack), pack Wskip, conv1 bias, feat.
// B-frag (mfma_f32_16x16x32_bf16): lane holds B[k=(lane>>4)*8+j][n=lane&15].
// bp1 index: [k][ct][lane][j] (27*4*64*8)
__global__ __launch_bounds__(256) void fold1_kernel(
    const float* __restrict__ W1, const float* __restrict__ gamma1,
    const float* __restrict__ beta1, const float* __restrict__ Wskip,
    const float* __restrict__ stats1,
    __bf16* __restrict__ bp1, __bf16* __restrict__ bps,
    float* __restrict__ bias1,
    const int* __restrict__ feat, int* __restrict__ feat_out, float inv_n)
{
    int b = blockIdx.x, t = threadIdx.x;
    if (b < 216) {
        int e = b * 256 + t;
        int j = e & 7, lane = (e >> 3) & 63, ct = (e >> 9) & 3, k = e >> 11;
        int ci = ((lane >> 4) << 3) + j;
        int co = (ct << 4) + (lane & 15);
        int g = ci >> 2;
        float mean = stats1[2 * g] * inv_n;
        float var  = stats1[2 * g + 1] * inv_n - mean * mean;
        float r = rsqrtf(var + 1e-5f);
        float a = gamma1[ci] * r;
        bp1[e] = (__bf16)(a * W1[k * 2048 + ci * 64 + co]);
    } else if (b == 216) {
        if (t < 64) {
            float sum = 0.0f;
            for (int ci = 0; ci < 32; ++ci) {
                int g = ci >> 2;
                float mean = stats1[2 * g] * inv_n;
                float var  = stats1[2 * g + 1] * inv_n - mean * mean;
                float r = rsqrtf(var + 1e-5f);
                float a = gamma1[ci] * r;
                float bb = beta1[ci] - mean * a;
                float ws = 0.0f;
                for (int k = 0; k < 27; ++k) ws += W1[k * 2048 + ci * 64 + t];
                sum += bb * ws;
            }
            bias1[t] = sum;
        } else if (t == 64) {
            feat_out[0] = feat[0];
        }
    } else {
        int e = (b - 217) * 256 + t;
        int j = e & 7, lane = (e >> 3) & 63, ct = e >> 9;
        int ci = ((lane >> 4) << 3) + j;
        int co = (ct << 4) + (lane & 15);
        bps[e] = (__bf16)Wskip[ci * 64 + co];
    }
}

// ---------------------------------------------------------------------------
// Fold GN2 into W2.  bp2 index: [k][hf][ct][lane][j]  (27*2*4*64*8)
__global__ __launch_bounds__(256) void fold2_kernel(
    const float* __restrict__ W2, const float* __restrict__ gamma2,
    const float* __restrict__ beta2, const float* __restrict__ stats2,
    __bf16* __restrict__ bp2, float* __restrict__ bias2, float inv_n)
{
    int b = blockIdx.x, t = threadIdx.x;
    if (b < 432) {
        int e = b * 256 + t;
        int j = e & 7, lane = (e >> 3) & 63, ct = (e >> 9) & 3, hf = (e >> 11) & 1, k = e >> 12;
        int ci = (hf << 5) + ((lane >> 4) << 3) + j;
        int co = (ct << 4) + (lane & 15);
        int g = ci >> 3;
        float mean = stats2[2 * g] * inv_n;
        float var  = stats2[2 * g + 1] * inv_n - mean * mean;
        float r = rsqrtf(var + 1e-5f);
        float a = gamma2[ci] * r;
        bp2[e] = (__bf16)(a * W2[k * 4096 + ci * 64 + co]);
    } else if (t < 64) {
        float sum = 0.0f;
        for (int ci = 0; ci < 64; ++ci) {
            int g = ci >> 3;
            float mean = stats2[2 * g] * inv_n;
            float var  = stats2[2 * g + 1] * inv_n - mean * mean;
            float r = rsqrtf(var + 1e-5f);
            float a = gamma2[ci] * r;
            float bb = beta2[ci] - mean * a;
            float ws = 0.0f;
            for (int k = 0; k < 27; ++k) ws += W2[k * 4096 + ci * 64 + t];
            sum += bb * ws;
        }
        bias2[t] = sum;
    }
}

// ---------------------------------------------------------------------------
// conv1: h[n,:64] = silu( sum_k xb[idx[n,k],:32] @ W1'[k] + bias1 )  (h bf16)
// + GN2 stats. 2 tiles (32 voxels) per wave, double-buffered tap prefetch.
__global__ __launch_bounds__(256, 4) void conv1_kernel(
    const __bf16* __restrict__ xb, const int* __restrict__ nbr,
    const __bf16* __restrict__ bp1, const float* __restrict__ bias1,
    __bf16* __restrict__ h, float* __restrict__ stats2, int nTiles)
{
    __shared__ int sidx[4][864];
    __shared__ float ls[16];
    const int wav = threadIdx.x >> 6, lane = threadIdx.x & 63;
    const int unit = blockIdx.x * 4 + wav;
    const int t0 = unit * 2;
    const bool act0 = t0 < nTiles, act1 = t0 + 1 < nTiles;
    if (threadIdx.x < 16) ls[threadIdx.x] = 0.f;
    const int lm = lane & 15, q = lane >> 4;
    f32x4 c[8] = {};
    if (act0) {
        const int* gi = nbr + (size_t)t0 * 432;
        const int cnt = act1 ? 864 : 432;
        for (int i = lane; i < 864; i += 64) sidx[wav][i] = (i < cnt) ? gi[i] : 0;
        const int* s0p = &sidx[wav][lm * 27];
        const int* s1p = &sidx[wav][432 + lm * 27];
        const bf16x8* __restrict__ bpv = (const bf16x8*)bp1;
        bf16x8 a0 = *(const bf16x8*)(xb + (size_t)s0p[0] * 32 + q * 8);
        bf16x8 a1 = *(const bf16x8*)(xb + (size_t)s1p[0] * 32 + q * 8);
#pragma unroll
        for (int k = 0; k < 27; ++k) {
            bf16x8 n0 = a0, n1 = a1;
            if (k < 26) {
                n0 = *(const bf16x8*)(xb + (size_t)s0p[k + 1] * 32 + q * 8);
                n1 = *(const bf16x8*)(xb + (size_t)s1p[k + 1] * 32 + q * 8);
            }
            int bb = k * 256 + lane;
            bf16x8 b0 = bpv[bb], b1 = bpv[bb + 64], b2 = bpv[bb + 128], b3 = bpv[bb + 192];
            c[0] = MFMA16(a0, b0, c[0]);
            c[1] = MFMA16(a0, b1, c[1]);
            c[2] = MFMA16(a0, b2, c[2]);
            c[3] = MFMA16(a0, b3, c[3]);
            c[4] = MFMA16(a1, b0, c[4]);
            c[5] = MFMA16(a1, b1, c[5]);
            c[6] = MFMA16(a1, b2, c[6]);
            c[7] = MFMA16(a1, b3, c[7]);
            a0 = n0; a1 = n1;
        }
    }
    __syncthreads();
    if (act0) {
        // C/D layout: col = lane&15 (cout), row = q*4 + r (voxel)
#define EPI1(CI, CT, V0) { \
        float bsv = bias1[(CT) * 16 + lm]; \
        float ps = 0.f, pss = 0.f; \
        _Pragma("unroll") \
        for (int r = 0; r < 4; ++r) { \
            float val = c[CI][r] + bsv; \
            val = val / (1.0f + __expf(-val)); \
            h[(size_t)((V0) + q * 4 + r) * 64 + (CT) * 16 + lm] = (__bf16)val; \
            ps += val; pss += val * val; } \
        int g2 = (CT) * 2 + (lm >> 3); \
        atomicAdd(&ls[2 * g2], ps); atomicAdd(&ls[2 * g2 + 1], pss); }
        const int v0 = t0 * 16;
        EPI1(0, 0, v0) EPI1(1, 1, v0) EPI1(2, 2, v0) EPI1(3, 3, v0)
        if (act1) {
            const int v1 = v0 + 16;
            EPI1(4, 0, v1) EPI1(5, 1, v1) EPI1(6, 2, v1) EPI1(7, 3, v1)
        }
#undef EPI1
    }
    __syncthreads();
    if (threadIdx.x < 16) atomicAdd(&stats2[threadIdx.x], ls[threadIdx.x]);
}

// ---------------------------------------------------------------------------
// conv2 + skip. 2 tiles per wave, double-buffered tap prefetch, no barriers.
__global__ __launch_bounds__(256, 4) void conv2_kernel(
    const __bf16* __restrict__ h, const __bf16* __restrict__ xb,
    const int* __restrict__ nbr,
    const __bf16* __restrict__ bp2, const __bf16* __restrict__ bps,
    const float* __restrict__ bias2, const float* __restrict__ bskip,
    float* __restrict__ out, int nTiles)
{
    __shared__ int sidx[4][864];
    const int wav = threadIdx.x >> 6, lane = threadIdx.x & 63;
    const int unit = blockIdx.x * 4 + wav;
    const int t0 = unit * 2;
    const bool act0 = t0 < nTiles, act1 = t0 + 1 < nTiles;
    if (!act0) return;
    const int lm = lane & 15, q = lane >> 4;
    const int* gi = nbr + (size_t)t0 * 432;
    const int cnt = act1 ? 864 : 432;
    for (int i = lane; i < 864; i += 64) sidx[wav][i] = (i < cnt) ? gi[i] : 0;
    const int* s0p = &sidx[wav][lm * 27];
    const int* s1p = &sidx[wav][432 + lm * 27];
    const bf16x8* __restrict__ bpv = (const bf16x8*)bp2;
    const bf16x8* __restrict__ bsp = (const bf16x8*)bps;
    f32x4 c[8] = {};
    {
        const __bf16* r0 = h + (size_t)s0p[0] * 64;
        const __bf16* r1 = h + (size_t)s1p[0] * 64;
        bf16x8 a0l = *(const bf16x8*)(r0 + q * 8);
        bf16x8 a0h = *(const bf16x8*)(r0 + 32 + q * 8);
        bf16x8 a1l = *(const bf16x8*)(r1 + q * 8);
        bf16x8 a1h = *(const bf16x8*)(r1 + 32 + q * 8);
#pragma unroll
        for (int k = 0; k < 27; ++k) {
            bf16x8 n0l = a0l, n0h = a0h, n1l = a1l, n1h = a1h;
            if (k < 26) {
                const __bf16* p0 = h + (size_t)s0p[k + 1] * 64;
                const __bf16* p1 = h + (size_t)s1p[k + 1] * 64;
                n0l = *(const bf16x8*)(p0 + q * 8);
                n0h = *(const bf16x8*)(p0 + 32 + q * 8);
                n1l = *(const bf16x8*)(p1 + q * 8);
                n1h = *(const bf16x8*)(p1 + 32 + q * 8);
            }
            int bb = k * 512 + lane;
            bf16x8 b0 = bpv[bb],       b1 = bpv[bb + 64];
            bf16x8 b2 = bpv[bb + 128], b3 = bpv[bb + 192];
            c[0] = MFMA16(a0l, b0, c[0]);
            c[1] = MFMA16(a0l, b1, c[1]);
            c[2] = MFMA16(a0l, b2, c[2]);
            c[3] = MFMA16(a0l, b3, c[3]);
            c[4] = MFMA16(a1l, b0, c[4]);
            c[5] = MFMA16(a1l, b1, c[5]);
            c[6] = MFMA16(a1l, b2, c[6]);
            c[7] = MFMA16(a1l, b3, c[7]);
            bf16x8 b4 = bpv[bb + 256], b5 = bpv[bb + 320];
            bf16x8 b6 = bpv[bb + 384], b7 = bpv[bb + 448];
            c[0] = MFMA16(a0h, b4, c[0]);
            c[1] = MFMA16(a0h, b5, c[1]);
            c[2] = MFMA16(a0h, b6, c[2]);
            c[3] = MFMA16(a0h, b7, c[3]);
            c[4] = MFMA16(a1h, b4, c[4]);
            c[5] = MFMA16(a1h, b5, c[5]);
            c[6] = MFMA16(a1h, b6, c[6]);
            c[7] = MFMA16(a1h, b7, c[7]);
            a0l = n0l; a0h = n0h; a1l = n1l; a1h = n1h;
        }
    }
    // skip 1x1 conv after the K-loop (short accumulator live range)
    f32x4 s[8] = {};
    {
        bf16x8 ax0 = *(const bf16x8*)(xb + ((size_t)t0 * 16 + lm) * 32 + q * 8);
        bf16x8 w0 = bsp[lane], w1 = bsp[64 + lane], w2 = bsp[128 + lane], w3 = bsp[192 + lane];
        s[0] = MFMA16(ax0, w0, s[0]);
        s[1] = MFMA16(ax0, w1, s[1]);
        s[2] = MFMA16(ax0, w2, s[2]);
        s[3] = MFMA16(ax0, w3, s[3]);
        if (act1) {
            bf16x8 ax1 = *(const bf16x8*)(xb + ((size_t)t0 * 16 + 16 + lm) * 32 + q * 8);
            s[4] = MFMA16(ax1, w0, s[4]);
            s[5] = MFMA16(ax1, w1, s[5]);
            s[6] = MFMA16(ax1, w2, s[6]);
            s[7] = MFMA16(ax1, w3, s[7]);
        }
    }
#define EPI2(CI, CT, V0) { \
        int co = (CT) * 16 + lm; \
        float b2v = bias2[co]; \
        float bsk = bskip[co]; \
        _Pragma("unroll") \
        for (int r = 0; r < 4; ++r) { \
            float val = c[CI][r] + b2v; \
            val = val / (1.0f + __expf(-val)); \
            val += s[CI][r] + bsk; \
            out[(size_t)((V0) + q * 4 + r) * 64 + co] = val; } }
    const int v0 = t0 * 16;
    EPI2(0, 0, v0) EPI2(1, 1, v0) EPI2(2, 2, v0) EPI2(3, 3, v0)
    if (act1) {
        const int v1 = v0 + 16;
        EPI2(4, 0, v1) EPI2(5, 1, v1) EPI2(6, 2, v1) EPI2(7, 3, v1)
    }
#undef EPI2
}

// ---------------------------------------------------------------------------
extern "C" void kernel_launch(void* const* d_in, const int* in_sizes, int n_in,
                              void* d_out, int out_size, void* d_ws, size_t ws_size,
                              hipStream_t stream)
{
    (void)n_in; (void)out_size; (void)ws_size;
    const float* x      = (const float*)d_in[0];
    const int*   nbr    = (const int*)d_in[1];
    const float* gamma1 = (const float*)d_in[2];
    const float* beta1  = (const float*)d_in[3];
    const float* W1     = (const float*)d_in[4];
    const float* gamma2 = (const float*)d_in[5];
    const float* beta2  = (const float*)d_in[6];
    const float* W2     = (const float*)d_in[7];
    const float* Wskip  = (const float*)d_in[8];
    const float* bskip  = (const float*)d_in[9];
    const int*   feat   = (const int*)d_in[10];
    const int N = in_sizes[0] / 32;

    char* ws = (char*)d_ws;
    float* stats1 = (float*)ws;                 // 16 floats
    float* stats2 = stats1 + 16;                // 16 floats
    float* bias1  = stats1 + 32;                // 64 floats
    float* bias2  = stats1 + 96;                // 64 floats
    __bf16* bp1 = (__bf16*)(ws + (1 << 10));    // 55296 elems
    __bf16* bps = (__bf16*)(ws + (1 << 17));    // 2048 elems
    __bf16* bp2 = (__bf16*)(ws + 144 * 1024);   // 110592 elems
    __bf16* xb  = (__bf16*)(ws + (1 << 20));    // N*32 bf16 = 32 MB
    __bf16* h   = (__bf16*)(ws + (size_t)34 * (1 << 20)); // N*64 bf16 = 64 MB
    float* outb = (float*)d_out;

    const int nTiles = (N + 15) / 16;           // 31250
    const int units = (nTiles + 1) / 2;         // 15625
    const int convBlocks = (units + 3) / 4;     // 3907

    hipLaunchKernelGGL(zero_stats_kernel, dim3(1), dim3(32), 0, stream, stats1);
    hipLaunchKernelGGL(caststats_kernel, dim3(2048), dim3(256), 0, stream,
                       (const float4*)x, (bf16x4*)xb, stats1, N * 8);
    hipLaunchKernelGGL(fold1_kernel, dim3(225), dim3(256), 0, stream,
                       W1, gamma1, beta1, Wskip, stats1, bp1, bps, bias1,
                       feat, (int*)(outb + (size_t)N * 64),
                       1.0f / (4.0f * (float)N));
    hipLaunchKernelGGL(conv1_kernel, dim3(convBlocks), dim3(256), 0, stream,
                       xb, nbr, bp1, bias1, h, stats2, nTiles);
    hipLaunchKernelGGL(fold2_kernel, dim3(433), dim3(256), 0, stream,
                       W2, gamma2, beta2, stats2, bp2, bias2,
                       1.0f / (8.0f * (float)N));
    hipLaunchKernelGGL(conv2_kernel, dim3(convBlocks), dim3(256), 0, stream,
                       h, xb, nbr, bp2, bps, bias2, bskip, outb, nTiles);
}